// Round 1
// baseline (931.674 us; speedup 1.0000x reference)
//
#include <hip/hip_runtime.h>
#include <hip/hip_bf16.h>

#define DD 256
#define NJ 512
#define KGC 64

__device__ inline float wave_reduce_sum(float v) {
  #pragma unroll
  for (int off = 32; off > 0; off >>= 1) v += __shfl_xor(v, off, 64);
  return v;
}
__device__ inline float wave_reduce_max(float v) {
  #pragma unroll
  for (int off = 32; off > 0; off >>= 1) v = fmaxf(v, __shfl_xor(v, off, 64));
  return v;
}

// ---------------------------------------------------------------------------
// Kernel 1: q,k,v projections. 8 rows per block, 256 threads (thread = out ch d).
// q,k immediately reduced against fc_w slices -> sq[row], sk[row]. v stored.
// ---------------------------------------------------------------------------
__global__ __launch_bounds__(256) void k_qkv(
    const float* __restrict__ vec,
    const float* __restrict__ Wq, const float* __restrict__ bq,
    const float* __restrict__ Wk, const float* __restrict__ bk,
    const float* __restrict__ Wv, const float* __restrict__ bv,
    const float* __restrict__ fc_w,
    float* __restrict__ v_out, float* __restrict__ sq_out, float* __restrict__ sk_out)
{
  const int R = 8;
  const int r0 = blockIdx.x * R;
  const int tid = threadIdx.x;
  const int lane = tid & 63, wid = tid >> 6;

  __shared__ float sx[R * DD];
  __shared__ float redq[R][4], redk[R][4];

  for (int idx = tid; idx < R * DD; idx += 256)
    sx[idx] = vec[(size_t)r0 * DD + idx];
  __syncthreads();

  const int d = tid;
  float aq[R], ak[R], av[R];
  const float bqd = bq[d], bkd = bk[d], bvd = bv[d];
  #pragma unroll
  for (int r = 0; r < R; r++) { aq[r] = bqd; ak[r] = bkd; av[r] = bvd; }

  for (int k = 0; k < DD; k++) {
    float wq = Wq[k * DD + d], wk = Wk[k * DD + d], wv = Wv[k * DD + d];
    #pragma unroll
    for (int r = 0; r < R; r++) {
      float x = sx[r * DD + k];
      aq[r] = fmaf(x, wq, aq[r]);
      ak[r] = fmaf(x, wk, ak[r]);
      av[r] = fmaf(x, wv, av[r]);
    }
  }

  const float fq = fc_w[d], fk = fc_w[DD + d];
  #pragma unroll
  for (int r = 0; r < R; r++) {
    float vq = fmaxf(aq[r], 0.f) * fq;
    float vk = fmaxf(ak[r], 0.f) * fk;
    vq = wave_reduce_sum(vq);
    vk = wave_reduce_sum(vk);
    if (lane == 0) { redq[r][wid] = vq; redk[r][wid] = vk; }
    v_out[(size_t)(r0 + r) * DD + d] = fmaxf(av[r], 0.f);
  }
  __syncthreads();
  if (tid < R) {
    sq_out[r0 + tid] = redq[tid][0] + redq[tid][1] + redq[tid][2] + redq[tid][3];
  } else if (tid < 2 * R) {
    int r = tid - R;
    sk_out[r0 + r] = redk[r][0] + redk[r][1] + redk[r][2] + redk[r][3];
  }
}

// ---------------------------------------------------------------------------
// Kernel 2: fused KG-gemv + relu + wkg_p dot + scores + leaky + softmax + PV
// + residual -> src. 4 query rows (i) per block, 512 threads (thread = j in
// the score phase; thread = (d, half) in the PV phase). Wkg/bkg/wkg_p indexed
// wave-uniformly -> scalar loads, FMAs run VGPR x SGPR.
// ---------------------------------------------------------------------------
__global__ __launch_bounds__(512) void k_attn(
    const float* __restrict__ KG,
    const float* __restrict__ Wkg, const float* __restrict__ bkg,
    const float* __restrict__ fc_w, const float* __restrict__ fc_b,
    const float* __restrict__ sq, const float* __restrict__ sk,
    const float* __restrict__ v, float* __restrict__ src_out)
{
  const int IT = 4;
  const int row0 = blockIdx.x * IT;          // global row = b*512 + i
  const int b = row0 >> 9;
  const int tid = threadIdx.x;
  const int lane = tid & 63, wid = tid >> 6;

  __shared__ float sw[IT][NJ];               // scores -> weights
  __shared__ float smax[8], ssum[8];
  __shared__ float sacc[512];

  const float* wkgp = fc_w + 2 * DD;
  const float fcb = fc_b[0];
  const int j = tid;
  const float skj = sk[b * NJ + j];

  #pragma unroll 1
  for (int ii = 0; ii < IT; ii++) {
    const int i = row0 + ii;
    const float* kgrow = KG + ((size_t)i * NJ + j) * KGC;
    float y[KGC];
    #pragma unroll
    for (int c = 0; c < KGC; c++) y[c] = bkg[c];

    #pragma unroll 1
    for (int cp = 0; cp < KGC; cp += 8) {
      float4 x0 = *(const float4*)(kgrow + cp);
      float4 x1 = *(const float4*)(kgrow + cp + 4);
      float x[8] = {x0.x, x0.y, x0.z, x0.w, x1.x, x1.y, x1.z, x1.w};
      #pragma unroll
      for (int u = 0; u < 8; u++) {
        #pragma unroll
        for (int c = 0; c < KGC; c++)
          y[c] = fmaf(x[u], Wkg[(cp + u) * KGC + c], y[c]);
      }
    }
    float skg = 0.f;
    #pragma unroll
    for (int c = 0; c < KGC; c++) skg = fmaf(fmaxf(y[c], 0.f), wkgp[c], skg);

    float sc = sq[i] + skj + skg + fcb;
    sc = sc > 0.f ? sc : 0.01f * sc;         // leaky_relu slope 0.01
    sw[ii][j] = sc;
  }
  __syncthreads();

  // softmax over j for each of the 4 rows
  #pragma unroll 1
  for (int ii = 0; ii < IT; ii++) {
    float x = sw[ii][tid];
    float m = wave_reduce_max(x);
    if (lane == 0) smax[wid] = m;
    __syncthreads();
    m = smax[0];
    #pragma unroll
    for (int w = 1; w < 8; w++) m = fmaxf(m, smax[w]);
    float e = __expf(x - m);
    float s = wave_reduce_sum(e);
    if (lane == 0) ssum[wid] = s;
    __syncthreads();
    s = 0.f;
    #pragma unroll
    for (int w = 0; w < 8; w++) s += ssum[w];
    sw[ii][tid] = e * (1.0f / s);
    __syncthreads();
  }

  // PV: attn_output = sum_j w[j] * v[b,j,:], split j-range over two halves
  const int d = tid & 255;
  const int half = tid >> 8;
  float acc[IT] = {0.f, 0.f, 0.f, 0.f};
  const float* vb = v + (size_t)b * NJ * DD;
  for (int jj = 0; jj < NJ / 2; jj++) {
    int jv = (half << 8) + jj;
    float vv = vb[(size_t)jv * DD + d];
    #pragma unroll
    for (int ii = 0; ii < IT; ii++) acc[ii] = fmaf(sw[ii][jv], vv, acc[ii]);
  }
  #pragma unroll 1
  for (int ii = 0; ii < IT; ii++) {
    sacc[tid] = acc[ii];
    __syncthreads();
    if (tid < 256) {
      float s = sacc[tid] + sacc[tid + 256];
      size_t o = (size_t)(row0 + ii) * DD + tid;
      src_out[o] = v[o] + s;                 // src = v + attn_output
    }
    __syncthreads();
  }
}

// ---------------------------------------------------------------------------
// Kernel 3: layernorm + MLP + residual. 8 rows per block, 256 threads.
// out = src + (leaky(LN(src) @ W1 + b1) @ W2 + b2)
// ---------------------------------------------------------------------------
__global__ __launch_bounds__(256) void k_mlp(
    const float* __restrict__ src,
    const float* __restrict__ ln_g, const float* __restrict__ ln_b,
    const float* __restrict__ W1, const float* __restrict__ b1,
    const float* __restrict__ W2, const float* __restrict__ b2,
    float* __restrict__ out)
{
  const int R = 8;
  const int r0 = blockIdx.x * R;
  const int tid = threadIdx.x;
  const int lane = tid & 63, wid = tid >> 6;

  __shared__ float sx[R * DD];
  __shared__ float h1[R * DD];
  __shared__ float smu[R], srs[R];

  for (int idx = tid; idx < R * DD; idx += 256)
    sx[idx] = src[(size_t)r0 * DD + idx];
  __syncthreads();

  // per-wave layernorm stats: wave wid handles rows wid, wid+4
  for (int r = wid; r < R; r += 4) {
    float s = 0.f, s2 = 0.f;
    #pragma unroll
    for (int u = 0; u < DD / 64; u++) {
      float x = sx[r * DD + u * 64 + lane];
      s += x;
      s2 = fmaf(x, x, s2);
    }
    s = wave_reduce_sum(s);
    s2 = wave_reduce_sum(s2);
    if (lane == 0) {
      float mu = s * (1.f / DD);
      float var = s2 * (1.f / DD) - mu * mu;
      smu[r] = mu;
      srs[r] = rsqrtf(var + 1e-5f);
    }
  }
  __syncthreads();
  for (int idx = tid; idx < R * DD; idx += 256) {
    int r = idx >> 8, k = idx & 255;
    sx[idx] = (sx[idx] - smu[r]) * srs[r] * ln_g[k] + ln_b[k];
  }
  __syncthreads();

  const int d = tid;
  float a1[R];
  const float b1d = b1[d];
  #pragma unroll
  for (int r = 0; r < R; r++) a1[r] = b1d;
  for (int k = 0; k < DD; k++) {
    float w = W1[k * DD + d];
    #pragma unroll
    for (int r = 0; r < R; r++) a1[r] = fmaf(sx[r * DD + k], w, a1[r]);
  }
  #pragma unroll
  for (int r = 0; r < R; r++) {
    float hv = a1[r];
    h1[r * DD + d] = hv > 0.f ? hv : 0.01f * hv;
  }
  __syncthreads();

  float a2[R];
  const float b2d = b2[d];
  #pragma unroll
  for (int r = 0; r < R; r++) a2[r] = b2d;
  for (int k = 0; k < DD; k++) {
    float w = W2[k * DD + d];
    #pragma unroll
    for (int r = 0; r < R; r++) a2[r] = fmaf(h1[r * DD + k], w, a2[r]);
  }
  #pragma unroll
  for (int r = 0; r < R; r++) {
    size_t o = (size_t)(r0 + r) * DD + d;
    out[o] = src[o] + a2[r];
  }
}

extern "C" void kernel_launch(void* const* d_in, const int* in_sizes, int n_in,
                              void* d_out, int out_size, void* d_ws, size_t ws_size,
                              hipStream_t stream) {
  const float* vectors = (const float*)d_in[0];
  const float* KG      = (const float*)d_in[1];
  const float* Wq      = (const float*)d_in[2];
  const float* bq      = (const float*)d_in[3];
  const float* Wk      = (const float*)d_in[4];
  const float* bk      = (const float*)d_in[5];
  const float* Wv      = (const float*)d_in[6];
  const float* bv      = (const float*)d_in[7];
  const float* Wkg     = (const float*)d_in[8];
  const float* bkg     = (const float*)d_in[9];
  const float* fc_w    = (const float*)d_in[10];
  const float* fc_b    = (const float*)d_in[11];
  const float* ln_g    = (const float*)d_in[12];
  const float* ln_b    = (const float*)d_in[13];
  const float* W1      = (const float*)d_in[14];
  const float* b1      = (const float*)d_in[15];
  const float* W2      = (const float*)d_in[16];
  const float* b2      = (const float*)d_in[17];
  // d_in[18]=Wo, d_in[19]=bo: unused by the reference.

  float* out = (float*)d_out;

  const int ROWS = 8 * 512;                  // B*N = 4096
  char* ws = (char*)d_ws;
  float* v_ws  = (float*)ws;                               // 4096*256
  float* sq_ws = (float*)(ws + (size_t)ROWS * DD * 4);     // 4096
  float* sk_ws = sq_ws + ROWS;                             // 4096
  float* src_ws = sk_ws + ROWS;                            // 4096*256

  k_qkv<<<ROWS / 8, 256, 0, stream>>>(vectors, Wq, bq, Wk, bk, Wv, bv, fc_w,
                                      v_ws, sq_ws, sk_ws);
  k_attn<<<ROWS / 4, 512, 0, stream>>>(KG, Wkg, bkg, fc_w, fc_b,
                                       sq_ws, sk_ws, v_ws, src_ws);
  k_mlp<<<ROWS / 8, 256, 0, stream>>>(src_ws, ln_g, ln_b, W1, b1, W2, b2, out);
}

// Round 2
// 839.488 us; speedup vs baseline: 1.1098x; 1.1098x over previous
//
#include <hip/hip_runtime.h>
#include <hip/hip_bf16.h>

#define DD 256
#define NJ 512
#define KGC 64

typedef float f32x4 __attribute__((ext_vector_type(4)));
typedef __bf16 bf16x8 __attribute__((ext_vector_type(8)));

__device__ inline float wave_reduce_sum(float v) {
  #pragma unroll
  for (int off = 32; off > 0; off >>= 1) v += __shfl_xor(v, off, 64);
  return v;
}
__device__ inline float wave_reduce_max(float v) {
  #pragma unroll
  for (int off = 32; off > 0; off >>= 1) v = fmaxf(v, __shfl_xor(v, off, 64));
  return v;
}

__device__ inline __bf16 bf16rne(float x) {
  unsigned u = __builtin_bit_cast(unsigned, x);
  u += 0x7fffu + ((u >> 16) & 1u);
  unsigned short h = (unsigned short)(u >> 16);
  return __builtin_bit_cast(__bf16, h);
}

// ---------------------------------------------------------------------------
// Kernel 1: q,k,v projections. 8 rows per block, 256 threads (thread = out ch d).
// Activations read with wave-uniform addresses -> s_load (SGPR operand to FMA).
// q,k immediately reduced against fc_w slices -> sq[row], sk[row]. v stored.
// ---------------------------------------------------------------------------
__global__ __launch_bounds__(256) void k_qkv(
    const float* __restrict__ vec,
    const float* __restrict__ Wq, const float* __restrict__ bq,
    const float* __restrict__ Wk, const float* __restrict__ bk,
    const float* __restrict__ Wv, const float* __restrict__ bv,
    const float* __restrict__ fc_w,
    float* __restrict__ v_out, float* __restrict__ sq_out, float* __restrict__ sk_out)
{
  const int R = 8;
  const int r0 = blockIdx.x * R;
  const int tid = threadIdx.x;
  const int lane = tid & 63, wid = tid >> 6;

  __shared__ float redq[R][4], redk[R][4];

  const int d = tid;
  float aq[R], ak[R], av[R];
  const float bqd = bq[d], bkd = bk[d], bvd = bv[d];
  #pragma unroll
  for (int r = 0; r < R; r++) { aq[r] = bqd; ak[r] = bkd; av[r] = bvd; }

  const float* xb = vec + (size_t)r0 * DD;

  for (int k = 0; k < DD; k += 4) {
    f32x4 xr[R];
    #pragma unroll
    for (int r = 0; r < R; r++) xr[r] = *(const f32x4*)&xb[r * DD + k];  // uniform -> s_load
    #pragma unroll
    for (int u = 0; u < 4; u++) {
      float wq = Wq[(k + u) * DD + d];
      float wk = Wk[(k + u) * DD + d];
      float wv = Wv[(k + u) * DD + d];
      #pragma unroll
      for (int r = 0; r < R; r++) {
        aq[r] = fmaf(xr[r][u], wq, aq[r]);
        ak[r] = fmaf(xr[r][u], wk, ak[r]);
        av[r] = fmaf(xr[r][u], wv, av[r]);
      }
    }
  }

  const float fq = fc_w[d], fk = fc_w[DD + d];
  #pragma unroll
  for (int r = 0; r < R; r++) {
    float vq = fmaxf(aq[r], 0.f) * fq;
    float vk = fmaxf(ak[r], 0.f) * fk;
    vq = wave_reduce_sum(vq);
    vk = wave_reduce_sum(vk);
    if (lane == 0) { redq[r][wid] = vq; redk[r][wid] = vk; }
    v_out[(size_t)(r0 + r) * DD + d] = fmaxf(av[r], 0.f);
  }
  __syncthreads();
  if (tid < R) {
    sq_out[r0 + tid] = redq[tid][0] + redq[tid][1] + redq[tid][2] + redq[tid][3];
  } else if (tid < 2 * R) {
    int r = tid - R;
    sk_out[r0 + r] = redk[r][0] + redk[r][1] + redk[r][2] + redk[r][3];
  }
}

// ---------------------------------------------------------------------------
// Kernel 2: scores via bf16 MFMA (KG @ Wkg, relu, dot wkg_p) + softmax + PV
// + residual. 4 query rows per block, 256 threads (4 waves). A-fragments
// loaded straight from global (coalesced, KG read exactly once). B-fragments
// (Wkg) built once into registers. C/D layout: col=lane&15, row=quad*4+reg.
// ---------------------------------------------------------------------------
__global__ __launch_bounds__(256) void k_attn(
    const float* __restrict__ KG,
    const float* __restrict__ Wkg, const float* __restrict__ bkg,
    const float* __restrict__ fc_w, const float* __restrict__ fc_b,
    const float* __restrict__ sq, const float* __restrict__ sk,
    const float* __restrict__ v, float* __restrict__ src_out)
{
  const int IT = 4;
  const int row0 = blockIdx.x * IT;          // global row = b*512 + i
  const int b = row0 >> 9;
  const int tid = threadIdx.x;
  const int lane = tid & 63, wid = tid >> 6;
  const int quad = lane >> 4, col = lane & 15;

  __shared__ __align__(16) float swT[NJ * IT];   // [j][ii]: raw skg -> weights
  __shared__ float smax[4][IT], ssum[4][IT];
  __shared__ __align__(16) f32x4 red[4][IT][64];

  // ---- one-time: B fragments (Wkg as bf16), bias and proj-weight lanes
  const float* wkgp = fc_w + 2 * DD;
  bf16x8 bfr[4][2];
  float bkgv[4], wkgv[4];
  #pragma unroll
  for (int nt = 0; nt < 4; nt++) {
    bkgv[nt] = bkg[nt * 16 + col];
    wkgv[nt] = wkgp[nt * 16 + col];
    #pragma unroll
    for (int t = 0; t < 2; t++) {
      #pragma unroll
      for (int j = 0; j < 8; j++)
        bfr[nt][t][j] = bf16rne(Wkg[(t * 32 + quad * 8 + j) * KGC + nt * 16 + col]);
    }
  }
  const float fcb = fc_b[0];

  // ---- phase 1: skg[j] for 4 rows, MFMA over 64-c contraction
  #pragma unroll 1
  for (int ii = 0; ii < IT; ii++) {
    const float* Ab = KG + (size_t)(row0 + ii) * NJ * KGC;
    #pragma unroll 1
    for (int mi = 0; mi < 8; mi++) {
      const int m0 = (wid * 8 + mi) * 16;
      const float* ar = Ab + (size_t)(m0 + col) * KGC + quad * 8;
      float4 p0 = *(const float4*)(ar);
      float4 p1 = *(const float4*)(ar + 4);
      float4 p2 = *(const float4*)(ar + 32);
      float4 p3 = *(const float4*)(ar + 36);
      bf16x8 a0, a1;
      a0[0] = bf16rne(p0.x); a0[1] = bf16rne(p0.y); a0[2] = bf16rne(p0.z); a0[3] = bf16rne(p0.w);
      a0[4] = bf16rne(p1.x); a0[5] = bf16rne(p1.y); a0[6] = bf16rne(p1.z); a0[7] = bf16rne(p1.w);
      a1[0] = bf16rne(p2.x); a1[1] = bf16rne(p2.y); a1[2] = bf16rne(p2.z); a1[3] = bf16rne(p2.w);
      a1[4] = bf16rne(p3.x); a1[5] = bf16rne(p3.y); a1[6] = bf16rne(p3.z); a1[7] = bf16rne(p3.w);

      f32x4 acc[4];
      #pragma unroll
      for (int nt = 0; nt < 4; nt++) {
        acc[nt] = (f32x4){0.f, 0.f, 0.f, 0.f};
        acc[nt] = __builtin_amdgcn_mfma_f32_16x16x32_bf16(a0, bfr[nt][0], acc[nt], 0, 0, 0);
        acc[nt] = __builtin_amdgcn_mfma_f32_16x16x32_bf16(a1, bfr[nt][1], acc[nt], 0, 0, 0);
      }

      float part[4];
      #pragma unroll
      for (int reg = 0; reg < 4; reg++) {
        float s = 0.f;
        #pragma unroll
        for (int nt = 0; nt < 4; nt++)
          s += fmaxf(acc[nt][reg] + bkgv[nt], 0.f) * wkgv[nt];
        part[reg] = s;
      }
      #pragma unroll
      for (int off = 1; off < 16; off <<= 1) {
        #pragma unroll
        for (int reg = 0; reg < 4; reg++)
          part[reg] += __shfl_xor(part[reg], off, 64);
      }
      if (col == 0) {
        #pragma unroll
        for (int reg = 0; reg < 4; reg++)
          swT[(m0 + quad * 4 + reg) * IT + ii] = part[reg];
      }
    }
  }
  __syncthreads();

  // ---- phase 2: softmax over j (512) for each of the 4 rows
  {
    const float sk0 = sk[b * NJ + tid];
    const float sk1 = sk[b * NJ + tid + 256];
    float x0[IT], x1[IT];
    #pragma unroll
    for (int ii = 0; ii < IT; ii++) {
      const float sqi = sq[row0 + ii];
      float a = swT[tid * IT + ii] + sk0 + sqi + fcb;
      float c = swT[(tid + 256) * IT + ii] + sk1 + sqi + fcb;
      a = a > 0.f ? a : 0.01f * a;
      c = c > 0.f ? c : 0.01f * c;
      x0[ii] = a; x1[ii] = c;
      float m = wave_reduce_max(fmaxf(a, c));
      if (lane == 0) smax[wid][ii] = m;
    }
    __syncthreads();
    #pragma unroll
    for (int ii = 0; ii < IT; ii++) {
      float m = fmaxf(fmaxf(smax[0][ii], smax[1][ii]), fmaxf(smax[2][ii], smax[3][ii]));
      float e0 = __expf(x0[ii] - m), e1 = __expf(x1[ii] - m);
      x0[ii] = e0; x1[ii] = e1;
      float s = wave_reduce_sum(e0 + e1);
      if (lane == 0) ssum[wid][ii] = s;
    }
    __syncthreads();
    #pragma unroll
    for (int ii = 0; ii < IT; ii++) {
      float s = ssum[0][ii] + ssum[1][ii] + ssum[2][ii] + ssum[3][ii];
      float iv = 1.f / s;
      swT[tid * IT + ii] = x0[ii] * iv;
      swT[(tid + 256) * IT + ii] = x1[ii] * iv;
    }
    __syncthreads();
  }

  // ---- phase 3: PV. Each wave owns 128 j's; lane owns 4 d's; reduce via LDS.
  {
    const float* vb = v + (size_t)b * NJ * DD;
    f32x4 pacc[IT];
    #pragma unroll
    for (int ii = 0; ii < IT; ii++) pacc[ii] = (f32x4){0.f, 0.f, 0.f, 0.f};
    const int j0 = wid * 128;
    for (int jj = 0; jj < 128; jj++) {
      const int jv = j0 + jj;
      f32x4 wv = *(const f32x4*)&swT[jv * IT];              // uniform -> broadcast
      f32x4 vv = *(const f32x4*)&vb[(size_t)jv * DD + lane * 4];
      #pragma unroll
      for (int ii = 0; ii < IT; ii++) pacc[ii] += wv[ii] * vv;
    }
    #pragma unroll
    for (int ii = 0; ii < IT; ii++) red[wid][ii][lane] = pacc[ii];
    __syncthreads();
    const int ii = tid >> 6, l = tid & 63;
    f32x4 s = red[0][ii][l] + red[1][ii][l] + red[2][ii][l] + red[3][ii][l];
    const size_t o = (size_t)(row0 + ii) * DD + l * 4;
    f32x4 vres = *(const f32x4*)&v[o];
    *(f32x4*)&src_out[o] = vres + s;                        // src = v + attn_out
  }
}

// ---------------------------------------------------------------------------
// Kernel 3: layernorm + MLP + residual. 8 rows per block, 256 threads.
// out = src + (leaky(LN(src) @ W1 + b1) @ W2 + b2). f32x4 LDS reads.
// ---------------------------------------------------------------------------
__global__ __launch_bounds__(256) void k_mlp(
    const float* __restrict__ src,
    const float* __restrict__ ln_g, const float* __restrict__ ln_b,
    const float* __restrict__ W1, const float* __restrict__ b1,
    const float* __restrict__ W2, const float* __restrict__ b2,
    float* __restrict__ out)
{
  const int R = 8;
  const int r0 = blockIdx.x * R;
  const int tid = threadIdx.x;
  const int lane = tid & 63, wid = tid >> 6;

  __shared__ __align__(16) float sx[R * DD];
  __shared__ __align__(16) float h1[R * DD];
  __shared__ float smu[R], srs[R];

  for (int idx = tid; idx < R * DD; idx += 256)
    sx[idx] = src[(size_t)r0 * DD + idx];
  __syncthreads();

  for (int r = wid; r < R; r += 4) {
    float s = 0.f, s2 = 0.f;
    #pragma unroll
    for (int u = 0; u < DD / 64; u++) {
      float x = sx[r * DD + u * 64 + lane];
      s += x;
      s2 = fmaf(x, x, s2);
    }
    s = wave_reduce_sum(s);
    s2 = wave_reduce_sum(s2);
    if (lane == 0) {
      float mu = s * (1.f / DD);
      float var = s2 * (1.f / DD) - mu * mu;
      smu[r] = mu;
      srs[r] = rsqrtf(var + 1e-5f);
    }
  }
  __syncthreads();
  for (int idx = tid; idx < R * DD; idx += 256) {
    int r = idx >> 8, k = idx & 255;
    sx[idx] = (sx[idx] - smu[r]) * srs[r] * ln_g[k] + ln_b[k];
  }
  __syncthreads();

  const int d = tid;
  float a1[R];
  const float b1d = b1[d];
  #pragma unroll
  for (int r = 0; r < R; r++) a1[r] = b1d;
  for (int k = 0; k < DD; k += 4) {
    f32x4 xr[R];
    #pragma unroll
    for (int r = 0; r < R; r++) xr[r] = *(const f32x4*)&sx[r * DD + k];
    #pragma unroll
    for (int u = 0; u < 4; u++) {
      float w = W1[(k + u) * DD + d];
      #pragma unroll
      for (int r = 0; r < R; r++) a1[r] = fmaf(xr[r][u], w, a1[r]);
    }
  }
  #pragma unroll
  for (int r = 0; r < R; r++) {
    float hv = a1[r];
    h1[r * DD + d] = hv > 0.f ? hv : 0.01f * hv;
  }
  __syncthreads();

  float a2[R];
  const float b2d = b2[d];
  #pragma unroll
  for (int r = 0; r < R; r++) a2[r] = b2d;
  for (int k = 0; k < DD; k += 4) {
    f32x4 xr[R];
    #pragma unroll
    for (int r = 0; r < R; r++) xr[r] = *(const f32x4*)&h1[r * DD + k];
    #pragma unroll
    for (int u = 0; u < 4; u++) {
      float w = W2[(k + u) * DD + d];
      #pragma unroll
      for (int r = 0; r < R; r++) a2[r] = fmaf(xr[r][u], w, a2[r]);
    }
  }
  #pragma unroll
  for (int r = 0; r < R; r++) {
    size_t o = (size_t)(r0 + r) * DD + d;
    out[o] = src[o] + a2[r];
  }
}

extern "C" void kernel_launch(void* const* d_in, const int* in_sizes, int n_in,
                              void* d_out, int out_size, void* d_ws, size_t ws_size,
                              hipStream_t stream) {
  const float* vectors = (const float*)d_in[0];
  const float* KG      = (const float*)d_in[1];
  const float* Wq      = (const float*)d_in[2];
  const float* bq      = (const float*)d_in[3];
  const float* Wk      = (const float*)d_in[4];
  const float* bk      = (const float*)d_in[5];
  const float* Wv      = (const float*)d_in[6];
  const float* bv      = (const float*)d_in[7];
  const float* Wkg     = (const float*)d_in[8];
  const float* bkg     = (const float*)d_in[9];
  const float* fc_w    = (const float*)d_in[10];
  const float* fc_b    = (const float*)d_in[11];
  const float* ln_g    = (const float*)d_in[12];
  const float* ln_b    = (const float*)d_in[13];
  const float* W1      = (const float*)d_in[14];
  const float* b1      = (const float*)d_in[15];
  const float* W2      = (const float*)d_in[16];
  const float* b2      = (const float*)d_in[17];
  // d_in[18]=Wo, d_in[19]=bo: unused by the reference.

  float* out = (float*)d_out;

  const int ROWS = 8 * 512;                  // B*N = 4096
  char* ws = (char*)d_ws;
  float* v_ws  = (float*)ws;                               // 4096*256
  float* sq_ws = (float*)(ws + (size_t)ROWS * DD * 4);     // 4096
  float* sk_ws = sq_ws + ROWS;                             // 4096
  float* src_ws = sk_ws + ROWS;                            // 4096*256

  k_qkv<<<ROWS / 8, 256, 0, stream>>>(vectors, Wq, bq, Wk, bk, Wv, bv, fc_w,
                                      v_ws, sq_ws, sk_ws);
  k_attn<<<ROWS / 4, 256, 0, stream>>>(KG, Wkg, bkg, fc_w, fc_b,
                                       sq_ws, sk_ws, v_ws, src_ws);
  k_mlp<<<ROWS / 8, 256, 0, stream>>>(src_ws, ln_g, ln_b, W1, b1, W2, b2, out);
}